// Round 2
// baseline (566.602 us; speedup 1.0000x reference)
//
#include <hip/hip_runtime.h>
#include <hip/hip_bf16.h>
#include <math.h>

typedef __bf16 bf16;
typedef bf16 bf16x8 __attribute__((ext_vector_type(8)));
typedef bf16 bf16x4 __attribute__((ext_vector_type(4)));
typedef float f32x4 __attribute__((ext_vector_type(4)));

#define NFRM 16
#define SEQ  1472
#define TOK  (NFRM * SEQ)   /* 23552 */
#define DIM_ 1024
#define NH_  16
#define HD_  64
#define KROW 1032           /* LDS row stride (bf16) for attn k/v: 1024 + 8 pad */

// Internal q/k/v/attn-out layout is T-MAJOR: row' = t*16 + f. GEMMs permute on
// the A-load side only (per-lane global source address; LDS stays linear).

__device__ __forceinline__ void load_lds_16B(const void* g, void* l) {
  __builtin_amdgcn_global_load_lds(
      (const __attribute__((address_space(1))) unsigned int*)g,
      (__attribute__((address_space(3))) unsigned int*)l,
      16, 0, 0);
}

// ---------------------------------------------------------------------------
__global__ __launch_bounds__(256) void cvt_bf16(const float* __restrict__ s,
                                                bf16* __restrict__ d, int n) {
  size_t i = ((size_t)blockIdx.x * 256 + threadIdx.x) * 8;
  if (i >= (size_t)n) return;
  f32x4 a = *(const f32x4*)(s + i);
  f32x4 b = *(const f32x4*)(s + i + 4);
  bf16x8 o;
  o[0] = (bf16)a[0]; o[1] = (bf16)a[1]; o[2] = (bf16)a[2]; o[3] = (bf16)a[3];
  o[4] = (bf16)b[0]; o[5] = (bf16)b[1]; o[6] = (bf16)b[2]; o[7] = (bf16)b[3];
  *(bf16x8*)(d + i) = o;
}

__global__ __launch_bounds__(256) void cvt_w4(
    const float* __restrict__ w0, const float* __restrict__ w1,
    const float* __restrict__ w2, const float* __restrict__ w3,
    bf16* __restrict__ d0, bf16* __restrict__ d1,
    bf16* __restrict__ d2, bf16* __restrict__ d3) {
  const int z = blockIdx.y;
  const float* s = (z == 0) ? w0 : (z == 1) ? w1 : (z == 2) ? w2 : w3;
  bf16* d       = (z == 0) ? d0 : (z == 1) ? d1 : (z == 2) ? d2 : d3;
  size_t i = ((size_t)blockIdx.x * 256 + threadIdx.x) * 8;
  f32x4 a = *(const f32x4*)(s + i);
  f32x4 b = *(const f32x4*)(s + i + 4);
  bf16x8 o;
  o[0] = (bf16)a[0]; o[1] = (bf16)a[1]; o[2] = (bf16)a[2]; o[3] = (bf16)a[3];
  o[4] = (bf16)b[0]; o[5] = (bf16)b[1]; o[6] = (bf16)b[2]; o[7] = (bf16)b[3];
  *(bf16x8*)(d + i) = o;
}

// ---------------------------------------------------------------------------
// 256x256-tile, BK=64, 8-wave (2M x 4N) double-buffered TRUE 8-phase GEMM
// (m201 template). Per K-tile: 4 phases, each {ds_read subtile | prefetch} ->
// barrier -> lgkmcnt(0) -> sched_barrier -> setprio(1) -> 16 MFMA ->
// setprio(0) -> [counted vmcnt pre-barrier] -> barrier.
// vmcnt(6) at end of phase 1 (covers cur tile A-steps 6,7); vmcnt(2) at end
// of phase 3 (covers next tile steps 0-5). Prefetch spread 3/3/2/0.
// Swizzle: byte ^= (row&7)<<4 on 16B chunks, applied on the staging *source*
// address (lane-constant XOR) and folded into read offsets.
// AMAP: 0 identity, 1: C row'=t*16+f reads A row f*SEQ+t, 2: inverse.
// ---------------------------------------------------------------------------
template <typename OutT, int AMAP>
__device__ __forceinline__ void gemm256_body(const bf16* __restrict__ A,
                                             const bf16* __restrict__ B,
                                             const float* __restrict__ bias,
                                             OutT* __restrict__ C,
                                             bf16* lds) {
  const int tid  = threadIdx.x;
  const int w    = tid >> 6;
  const int lane = tid & 63;
  const int am0  = blockIdx.x * 256;
  const int bn0  = blockIdx.y * 256;

  // ---- staging setup: 8 steps/K-tile, 64 rows x 128B each ----
  const int rstep = w * 8 + (lane >> 3);                  // row within a step
  const int jsrc  = ((lane & 7) ^ ((lane >> 3) & 7)) * 8; // swizzled src chunk
  const int arb[4] = {0, 128, 64, 192};                   // A step row bases
  const bf16* srcp[8];
  int dstoff[8];
#pragma unroll
  for (int s = 0; s < 4; ++s) {
    // steps 0-3: B rows (needed by every wave's phase 0 -> staged first)
    srcp[s]   = B + (size_t)(bn0 + s * 64 + rstep) * DIM_ + jsrc;
    dstoff[s] = 32768 + s * 8192 + w * 1024;
    // steps 4-7: A rows {0-63,128-191,64-127,192-255} (phases 0-1 use 4,5;
    // phases 2-3 use 6,7)
    int R = am0 + arb[s] + rstep;
    size_t ar;
    if (AMAP == 1)      ar = (size_t)(R & 15) * SEQ + (R >> 4);
    else if (AMAP == 2) { unsigned f = (unsigned)R / SEQ;
                          ar = (size_t)(R - (int)f * SEQ) * 16 + f; }
    else                 ar = (size_t)R;
    srcp[4 + s]   = A + ar * DIM_ + jsrc;
    dstoff[4 + s] = arb[s] * 128 + w * 1024;
  }

  // ---- fragment read offsets (bytes, swizzle folded in) ----
  const int wr   = w >> 2;       // 0..1  (M half)
  const int wc   = w & 3;        // 0..3  (N quarter)
  const int frow = lane & 15;
  const int g    = lane >> 4;
  const int sw   = (frow & 7) << 4;
  const int e0   = (g * 16) ^ sw;        // k-step 0
  const int e1   = (g * 16 + 64) ^ sw;   // k-step 1
  const int aA   = (wr * 128 + frow) * 128;
  const int bB   = 32768 + (wc * 64 + frow) * 128;

  f32x4 acc[8][4];
#pragma unroll
  for (int i = 0; i < 8; ++i)
#pragma unroll
    for (int j = 0; j < 4; ++j) {
      f32x4 z = {0.f, 0.f, 0.f, 0.f};
      acc[i][j] = z;
    }

  char* ldsc = (char*)lds;

  // prologue: stage K-tile 0 into buf0 (issue order 0..7, fixed for vmcnt
  // ledger); then wait steps 0-5 + barrier so phase 0/1 reads are valid.
#pragma unroll
  for (int s = 0; s < 8; ++s) load_lds_16B(srcp[s], ldsc + dstoff[s]);
  asm volatile("s_waitcnt vmcnt(2)" ::: "memory");
  asm volatile("s_barrier" ::: "memory");

#pragma unroll 1
  for (int it = 0; it < 8; ++it) {
#pragma unroll
    for (int half = 0; half < 2; ++half) {
      const int kt   = it * 2 + half;
      const int cur  = half ? 65536 : 0;
      const int nxt  = half ? 0 : 65536;
      const int kpre = (kt < 15) ? (kt + 1) * 64 : 15 * 64;  // dummy at kt=15

      bf16x8 bfv[4][2];

#pragma unroll
      for (int p = 0; p < 4; ++p) {
        // ---- memory window: ds_read this phase's fragments + prefetch ----
        if (p == 0) {
#pragma unroll
          for (int j = 0; j < 4; ++j) {
            bfv[j][0] = *(const bf16x8*)(ldsc + cur + bB + j * 2048 + e0);
            bfv[j][1] = *(const bf16x8*)(ldsc + cur + bB + j * 2048 + e1);
          }
        }
        bf16x8 af[2][2];
#pragma unroll
        for (int ii = 0; ii < 2; ++ii) {
          const int i = p * 2 + ii;
          af[ii][0] = *(const bf16x8*)(ldsc + cur + aA + i * 2048 + e0);
          af[ii][1] = *(const bf16x8*)(ldsc + cur + aA + i * 2048 + e1);
        }
        if (p == 0) {
          load_lds_16B(srcp[0] + kpre, ldsc + nxt + dstoff[0]);
          load_lds_16B(srcp[1] + kpre, ldsc + nxt + dstoff[1]);
          load_lds_16B(srcp[2] + kpre, ldsc + nxt + dstoff[2]);
        } else if (p == 1) {
          load_lds_16B(srcp[3] + kpre, ldsc + nxt + dstoff[3]);
          load_lds_16B(srcp[4] + kpre, ldsc + nxt + dstoff[4]);
          load_lds_16B(srcp[5] + kpre, ldsc + nxt + dstoff[5]);
        } else if (p == 2) {
          load_lds_16B(srcp[6] + kpre, ldsc + nxt + dstoff[6]);
          load_lds_16B(srcp[7] + kpre, ldsc + nxt + dstoff[7]);
        }

        // ---- compute window ----
        asm volatile("s_barrier" ::: "memory");
        asm volatile("s_waitcnt lgkmcnt(0)" ::: "memory");
        __builtin_amdgcn_sched_barrier(0);   // rule #18: pin MFMA below wait
        __builtin_amdgcn_s_setprio(1);
#pragma unroll
        for (int ii = 0; ii < 2; ++ii) {
          const int i = p * 2 + ii;
#pragma unroll
          for (int j = 0; j < 4; ++j) {
            acc[i][j] = __builtin_amdgcn_mfma_f32_16x16x32_bf16(
                af[ii][0], bfv[j][0], acc[i][j], 0, 0, 0);
            acc[i][j] = __builtin_amdgcn_mfma_f32_16x16x32_bf16(
                af[ii][1], bfv[j][1], acc[i][j], 0, 0, 0);
          }
        }
        __builtin_amdgcn_s_setprio(0);
        __builtin_amdgcn_sched_barrier(0);   // keep cluster inside the phase

        // ---- counted waits, pre-barrier (barrier => all waves' loads in) --
        if (p == 1) asm volatile("s_waitcnt vmcnt(6)" ::: "memory");
        if (p == 3) asm volatile("s_waitcnt vmcnt(2)" ::: "memory");
        asm volatile("s_barrier" ::: "memory");
      }
    }
  }

  // epilogue: C[row=am0+wr*128+i*16+(lane>>4)*4+r][col=bn0+wc*64+j*16+(lane&15)]
  const int cl = lane & 15;
  const int rq = g * 4;
#pragma unroll
  for (int j = 0; j < 4; ++j) {
    const int nc   = bn0 + wc * 64 + j * 16 + cl;
    const float bb = bias[nc];
#pragma unroll
    for (int i = 0; i < 8; ++i) {
#pragma unroll
      for (int r = 0; r < 4; ++r) {
        const size_t mr = (size_t)am0 + wr * 128 + i * 16 + rq + r;
        C[mr * DIM_ + nc] = (OutT)(acc[i][j][r] + bb);
      }
    }
  }
}

__global__ __launch_bounds__(512, 2) void gemm_qkv(
    const bf16* __restrict__ A,
    const bf16* __restrict__ Bq, const bf16* __restrict__ Bk,
    const bf16* __restrict__ Bv,
    const float* __restrict__ bq, const float* __restrict__ bk,
    const float* __restrict__ bv,
    bf16* __restrict__ Cq, bf16* __restrict__ Ck, bf16* __restrict__ Cv) {
  __shared__ __align__(16) bf16 lds[65536];  // 128 KiB
  const int z = blockIdx.z;
  const bf16* B    = (z == 0) ? Bq : (z == 1) ? Bk : Bv;
  const float* bia = (z == 0) ? bq : (z == 1) ? bk : bv;
  bf16* C          = (z == 0) ? Cq : (z == 1) ? Ck : Cv;
  gemm256_body<bf16, 1>(A, B, bia, C, lds);
}

__global__ __launch_bounds__(512, 2) void gemm_out(
    const bf16* __restrict__ A, const bf16* __restrict__ B,
    const float* __restrict__ bias, float* __restrict__ C) {
  __shared__ __align__(16) bf16 lds[65536];
  gemm256_body<float, 2>(A, B, bias, C, lds);
}

// ---------------------------------------------------------------------------
// In-place RMSNorm + RoPE on t-major rows. Wave per row, 4 rows per block.
// ---------------------------------------------------------------------------
__global__ __launch_bounds__(256) void norm_rope(
    bf16* __restrict__ q, bf16* __restrict__ k,
    const float* __restrict__ nqw, const float* __restrict__ nkw,
    const float* __restrict__ fcos, const float* __restrict__ fsin) {
  const int lane = threadIdx.x & 63, wave = threadIdx.x >> 6;
  const size_t row  = (size_t)blockIdx.x * 4 + wave;   // t-major row'
  const size_t base = row * DIM_;
  const size_t pos  = (row & 15) * (size_t)SEQ + (row >> 4);  // f*SEQ + t
  const int e0 = lane * 16;
  const int j0 = (lane & 3) * 8;

  float cs[8], sn[8];
#pragma unroll
  for (int i = 0; i < 8; ++i) {
    cs[i] = fcos[pos * 32 + j0 + i];
    sn[i] = fsin[pos * 32 + j0 + i];
  }

  bf16x8 qa = *(const bf16x8*)(q + base + e0);
  bf16x8 qb = *(const bf16x8*)(q + base + e0 + 8);
  bf16x8 ka = *(const bf16x8*)(k + base + e0);
  bf16x8 kb = *(const bf16x8*)(k + base + e0 + 8);

  float xq[16], xk[16];
#pragma unroll
  for (int i = 0; i < 8; ++i) {
    xq[i] = (float)qa[i]; xq[8 + i] = (float)qb[i];
    xk[i] = (float)ka[i]; xk[8 + i] = (float)kb[i];
  }
  float sq = 0.f, sk = 0.f;
#pragma unroll
  for (int i = 0; i < 16; ++i) { sq += xq[i] * xq[i]; sk += xk[i] * xk[i]; }
#pragma unroll
  for (int off = 32; off > 0; off >>= 1) {
    sq += __shfl_xor(sq, off);
    sk += __shfl_xor(sk, off);
  }
  const float rq = rsqrtf(sq * (1.0f / 1024.0f) + 1e-6f);
  const float rk = rsqrtf(sk * (1.0f / 1024.0f) + 1e-6f);
#pragma unroll
  for (int i = 0; i < 16; ++i) {
    xq[i] *= rq * nqw[e0 + i];
    xk[i] *= rk * nkw[e0 + i];
  }
  bf16x8 oa, ob, oc, od;
#pragma unroll
  for (int p = 0; p < 8; ++p) {
    const float c = cs[p], s = sn[p];
    const float q0 = xq[2 * p], q1 = xq[2 * p + 1];
    const float k0 = xk[2 * p], k1 = xk[2 * p + 1];
    const float qr = q0 * c - q1 * s, qi = q0 * s + q1 * c;
    const float kr = k0 * c - k1 * s, ki = k0 * s + k1 * c;
    if (p < 4) { oa[2 * p] = (bf16)qr; oa[2 * p + 1] = (bf16)qi;
                 oc[2 * p] = (bf16)kr; oc[2 * p + 1] = (bf16)ki; }
    else       { ob[2 * p - 8] = (bf16)qr; ob[2 * p - 7] = (bf16)qi;
                 od[2 * p - 8] = (bf16)kr; od[2 * p - 7] = (bf16)ki; }
  }
  *(bf16x8*)(q + base + e0)     = oa;
  *(bf16x8*)(q + base + e0 + 8) = ob;
  *(bf16x8*)(k + base + e0)     = oc;
  *(bf16x8*)(k + base + e0 + 8) = od;
}

// ---------------------------------------------------------------------------
// Windowed attention, t-major layout: block per t, all data in one 32KB slab.
// ---------------------------------------------------------------------------
__global__ __launch_bounds__(512, 4) void attn_win(
    const bf16* __restrict__ q, const bf16* __restrict__ k,
    const bf16* __restrict__ v, bf16* __restrict__ o) {
  __shared__ __align__(16) bf16 ks[16 * KROW];
  __shared__ __align__(16) bf16 vs[16 * KROW];
  __shared__ __align__(16) bf16 ps[16 * 256];  // [h][fq][fk]
  const int t    = blockIdx.x;
  const int tid  = threadIdx.x;
  const int wave = tid >> 6, lane = tid & 63;
  const size_t tb = (size_t)t * (16 * DIM_);   // base elem of t's slab

  // phase 1: stream k,v (2 x 32KB contiguous) into LDS
#pragma unroll
  for (int i = 0; i < 4; ++i) {
    const int j = wave * 4 + i;  // 0..31
    const int r = j >> 1, half = j & 1;
    const size_t g = tb + (size_t)r * DIM_ + half * 512 + lane * 8;
    load_lds_16B(k + g, ks + r * KROW + half * 512);
    load_lds_16B(v + g, vs + r * KROW + half * 512);
  }
  __syncthreads();

  // phase 2: scores via MFMA + softmax; wave handles heads wave*2, wave*2+1
  const int fl  = lane & 15;
  const int kq  = (lane >> 4) * 8;
#pragma unroll
  for (int hh = 0; hh < 2; ++hh) {
    const int h = wave * 2 + hh;
    const size_t qg = tb + (size_t)fl * DIM_ + h * HD_ + kq;
    bf16x8 aq0 = *(const bf16x8*)(q + qg);
    bf16x8 aq1 = *(const bf16x8*)(q + qg + 32);
    const int ko = fl * KROW + h * HD_ + kq;
    bf16x8 bk0 = *(const bf16x8*)(ks + ko);
    bf16x8 bk1 = *(const bf16x8*)(ks + ko + 32);
    f32x4 sc = {0.f, 0.f, 0.f, 0.f};
    sc = __builtin_amdgcn_mfma_f32_16x16x32_bf16(aq0, bk0, sc, 0, 0, 0);
    sc = __builtin_amdgcn_mfma_f32_16x16x32_bf16(aq1, bk1, sc, 0, 0, 0);
#pragma unroll
    for (int r = 0; r < 4; ++r) {
      const int row = (lane >> 4) * 4 + r;  // fq
      const bool valid = (fl <= row) && (row - fl < 8);
      float s = valid ? sc[r] * 0.125f : -1e30f;
      float m = s;
#pragma unroll
      for (int off = 8; off > 0; off >>= 1) m = fmaxf(m, __shfl_xor(m, off));
      const float e = __expf(s - m);
      float su = e;
#pragma unroll
      for (int off = 8; off > 0; off >>= 1) su += __shfl_xor(su, off);
      ps[h * 256 + row * 16 + fl] = (bf16)(e / su);
    }
  }
  __syncthreads();

  // phase 3: PV, register-blocked. thread = (h, d-chunk, fq-group)
  const int h3 = tid >> 5;
  const int dc = (tid >> 2) & 7;
  const int fg = tid & 3;
  bf16x8 pr[8];
#pragma unroll
  for (int i = 0; i < 4; ++i) {
    pr[2 * i]     = *(const bf16x8*)(ps + h3 * 256 + (fg * 4 + i) * 16);
    pr[2 * i + 1] = *(const bf16x8*)(ps + h3 * 256 + (fg * 4 + i) * 16 + 8);
  }
  float acc[4][8];
#pragma unroll
  for (int i = 0; i < 4; ++i)
#pragma unroll
    for (int d = 0; d < 8; ++d) acc[i][d] = 0.f;

  const bf16* vb = vs + h3 * HD_ + dc * 8;
#pragma unroll
  for (int fk2 = 0; fk2 < 16; ++fk2) {
    bf16x8 vv8 = *(const bf16x8*)(vb + fk2 * KROW);
    float vf[8];
#pragma unroll
    for (int d = 0; d < 8; ++d) vf[d] = (float)vv8[d];
#pragma unroll
    for (int i = 0; i < 4; ++i) {
      const float pp = (float)((fk2 < 8) ? pr[2 * i][fk2] : pr[2 * i + 1][fk2 - 8]);
#pragma unroll
      for (int d = 0; d < 8; ++d) acc[i][d] += pp * vf[d];
    }
  }
#pragma unroll
  for (int i = 0; i < 4; ++i) {
    bf16x8 ov;
#pragma unroll
    for (int d = 0; d < 8; ++d) ov[d] = (bf16)acc[i][d];
    *(bf16x8*)(o + tb + (size_t)(fg * 4 + i) * DIM_ + h3 * HD_ + dc * 8) = ov;
  }
}

// ---------------------------------------------------------------------------
extern "C" void kernel_launch(void* const* d_in, const int* in_sizes, int n_in,
                              void* d_out, int out_size, void* d_ws,
                              size_t ws_size, hipStream_t stream) {
  const float* x    = (const float*)d_in[0];
  const float* fcos = (const float*)d_in[1];
  const float* fsin = (const float*)d_in[2];
  const float* q_w  = (const float*)d_in[3];
  const float* q_b  = (const float*)d_in[4];
  const float* k_w  = (const float*)d_in[5];
  const float* k_b  = (const float*)d_in[6];
  const float* v_w  = (const float*)d_in[7];
  const float* v_b  = (const float*)d_in[8];
  const float* o_w  = (const float*)d_in[9];
  const float* o_b  = (const float*)d_in[10];
  const float* nqw  = (const float*)d_in[11];
  const float* nkw  = (const float*)d_in[12];
  float* out = (float*)d_out;

  char* ws = (char*)d_ws;
  const size_t SZ  = (size_t)TOK * DIM_ * 2;
  const size_t WSZ = (size_t)DIM_ * DIM_ * 2;
  bf16* xb = (bf16*)(ws);
  bf16* wq = (bf16*)(ws + SZ);
  bf16* wk = (bf16*)(ws + SZ + WSZ);
  bf16* wv = (bf16*)(ws + SZ + 2 * WSZ);
  bf16* wo = (bf16*)(ws + SZ + 3 * WSZ);
  bf16* qq = (bf16*)(ws + SZ + 4 * WSZ);
  bf16* kk = (bf16*)(ws + SZ + 4 * WSZ + SZ);
  bf16* vv = (bf16*)(ws + SZ + 4 * WSZ + 2 * SZ);
  bf16* om = xb;  // x_bf16 dead after gemm_qkv; reuse for attention output

  const int NTOT = TOK * DIM_;
  const int NW   = DIM_ * DIM_;

  cvt_bf16<<<NTOT / 2048, 256, 0, stream>>>(x, xb, NTOT);
  cvt_w4<<<dim3(NW / 2048, 4), 256, 0, stream>>>(q_w, k_w, v_w, o_w,
                                                 wq, wk, wv, wo);

  dim3 gq(TOK / 256, DIM_ / 256, 3);  // (92, 4, 3)
  gemm_qkv<<<gq, 512, 0, stream>>>(xb, wq, wk, wv, q_b, k_b, v_b, qq, kk, vv);

  norm_rope<<<TOK / 4, 256, 0, stream>>>(qq, kk, nqw, nkw, fcos, fsin);

  attn_win<<<SEQ, 512, 0, stream>>>(qq, kk, vv, om);

  gemm_out<<<dim3(TOK / 256, DIM_ / 256), 512, 0, stream>>>(om, wo, o_b, out);
}

// Round 3
// 536.538 us; speedup vs baseline: 1.0560x; 1.0560x over previous
//
#include <hip/hip_runtime.h>
#include <hip/hip_bf16.h>
#include <math.h>

typedef __bf16 bf16;
typedef bf16 bf16x8 __attribute__((ext_vector_type(8)));
typedef bf16 bf16x4 __attribute__((ext_vector_type(4)));
typedef float f32x4 __attribute__((ext_vector_type(4)));

#define NFRM 16
#define SEQ  1472
#define TOK  (NFRM * SEQ)   /* 23552 */
#define DIM_ 1024
#define NH_  16
#define HD_  64
#define KROW 1032           /* LDS row stride (bf16) for attn k/v: 1024 + 8 pad */

// Internal layout is T-MAJOR everywhere: row' = t*16 + f. x is permuted to
// t-major at the cvt step, so BOTH GEMMs stage A with contiguous panels.
// gemm_out permutes rows on the C-write side (stores are latency-tolerant).

__device__ __forceinline__ void load_lds_16B(const void* g, void* l) {
  __builtin_amdgcn_global_load_lds(
      (const __attribute__((address_space(1))) unsigned int*)g,
      (__attribute__((address_space(3))) unsigned int*)l,
      16, 0, 0);
}

// ---------------------------------------------------------------------------
// f32 -> bf16 with f-major -> t-major row permutation. Reads are linear;
// writes are 2KB-contiguous per input row (threads of a row write one row').
__global__ __launch_bounds__(256) void cvt_bf16(const float* __restrict__ s,
                                                bf16* __restrict__ d, int n) {
  size_t i = ((size_t)blockIdx.x * 256 + threadIdx.x) * 8;
  if (i >= (size_t)n) return;
  const int r   = (int)(i >> 10);       // natural row = f*SEQ + t
  const int col = (int)(i & 1023);
  const int f   = r / SEQ;
  const int t   = r - f * SEQ;
  const size_t o = ((size_t)(t * 16 + f) << 10) + col;
  f32x4 a = *(const f32x4*)(s + i);
  f32x4 b = *(const f32x4*)(s + i + 4);
  bf16x8 v;
  v[0] = (bf16)a[0]; v[1] = (bf16)a[1]; v[2] = (bf16)a[2]; v[3] = (bf16)a[3];
  v[4] = (bf16)b[0]; v[5] = (bf16)b[1]; v[6] = (bf16)b[2]; v[7] = (bf16)b[3];
  *(bf16x8*)(d + o) = v;
}

__global__ __launch_bounds__(256) void cvt_w4(
    const float* __restrict__ w0, const float* __restrict__ w1,
    const float* __restrict__ w2, const float* __restrict__ w3,
    bf16* __restrict__ d0, bf16* __restrict__ d1,
    bf16* __restrict__ d2, bf16* __restrict__ d3) {
  const int z = blockIdx.y;
  const float* s = (z == 0) ? w0 : (z == 1) ? w1 : (z == 2) ? w2 : w3;
  bf16* d       = (z == 0) ? d0 : (z == 1) ? d1 : (z == 2) ? d2 : d3;
  size_t i = ((size_t)blockIdx.x * 256 + threadIdx.x) * 8;
  f32x4 a = *(const f32x4*)(s + i);
  f32x4 b = *(const f32x4*)(s + i + 4);
  bf16x8 o;
  o[0] = (bf16)a[0]; o[1] = (bf16)a[1]; o[2] = (bf16)a[2]; o[3] = (bf16)a[3];
  o[4] = (bf16)b[0]; o[5] = (bf16)b[1]; o[6] = (bf16)b[2]; o[7] = (bf16)b[3];
  *(bf16x8*)(d + i) = o;
}

// ---------------------------------------------------------------------------
// XCD-grouping swizzle for a 92x4 plane (368 = 8*46 blocks). Hardware assigns
// consecutive ids round-robin across 8 XCDs; s=(h&7)*46+(h>>3) gives XCD c the
// consecutive work range [46c,46c+46) -> the 4 y-sharers of an A-panel run
// adjacently on ONE XCD (panel filled into one L2), B set/XCD = 2MB (fits).
__device__ __forceinline__ void swz368(int h, int& bx, int& by) {
  const int s = (h & 7) * 46 + (h >> 3);
  bx = s >> 2;
  by = s & 3;
}

// ---------------------------------------------------------------------------
// 256x256-tile, BK=64, 8-wave (2M x 4N) double-buffered GEMM, coarse 2-wait
// schedule (best measured). A rows contiguous (t-major input). OMAP: 0 = C
// rows t-major (identity), 1 = C row' t*16+f scattered to natural f*SEQ+t.
// Swizzle: byte ^= (row&7)<<4 on 16B chunks, applied on the staging *source*
// address (lane-constant XOR) and folded into read offsets.
// ---------------------------------------------------------------------------
template <typename OutT, int OMAP>
__device__ __forceinline__ void gemm256_body(const bf16* __restrict__ A,
                                             const bf16* __restrict__ B,
                                             const float* __restrict__ bias,
                                             OutT* __restrict__ C,
                                             bf16* lds, int bx, int by) {
  const int tid  = threadIdx.x;
  const int w    = tid >> 6;
  const int lane = tid & 63;
  const int am0  = bx * 256;
  const int bn0  = by * 256;

  // ---- staging setup: 8 steps/K-tile, 64 rows x 128B each ----
  const int rstep = w * 8 + (lane >> 3);                  // row within a step
  const int jsrc  = ((lane & 7) ^ ((lane >> 3) & 7)) * 8; // swizzled src chunk
  const int arb[4] = {0, 128, 64, 192};                   // A step row bases
  const bf16* srcp[8];
  int dstoff[8];
#pragma unroll
  for (int s = 0; s < 4; ++s) {
    // steps 0-3: B rows (needed by every wave's phase 0 -> staged first)
    srcp[s]   = B + (size_t)(bn0 + s * 64 + rstep) * DIM_ + jsrc;
    dstoff[s] = 32768 + s * 8192 + w * 1024;
    // steps 4-7: A rows {0-63,128-191,64-127,192-255} (quarter-interleaved);
    // contiguous panel streaming (identity row map).
    srcp[4 + s]   = A + (size_t)(am0 + arb[s] + rstep) * DIM_ + jsrc;
    dstoff[4 + s] = arb[s] * 128 + w * 1024;
  }

  // ---- fragment read offsets (bytes, swizzle folded in) ----
  const int wr   = w >> 2;       // 0..1  (M half)
  const int wc   = w & 3;        // 0..3  (N quarter)
  const int frow = lane & 15;
  const int g    = lane >> 4;
  const int sw   = (frow & 7) << 4;
  const int e0   = (g * 16) ^ sw;        // k-step 0
  const int e1   = (g * 16 + 64) ^ sw;   // k-step 1
  const int aA   = (wr * 128 + frow) * 128;
  const int bB   = 32768 + (wc * 64 + frow) * 128;

  f32x4 acc[8][4];
#pragma unroll
  for (int i = 0; i < 8; ++i)
#pragma unroll
    for (int j = 0; j < 4; ++j) {
      f32x4 z = {0.f, 0.f, 0.f, 0.f};
      acc[i][j] = z;
    }

  char* ldsc = (char*)lds;

  // prologue: stage K-tile 0 into buf0 (issue order 0..7 fixed for vmcnt math)
#pragma unroll
  for (int s = 0; s < 8; ++s) load_lds_16B(srcp[s], ldsc + dstoff[s]);

#pragma unroll 1
  for (int it = 0; it < 8; ++it) {
#pragma unroll
    for (int half = 0; half < 2; ++half) {
      const int kt   = it * 2 + half;
      const int cur  = half ? 65536 : 0;
      const int nxt  = half ? 0 : 65536;
      const int kpre = (kt < 15) ? (kt + 1) * 64 : 15 * 64;  // dummy at kt=15

      // phase 0: wait kt steps 0-5 (B + A quarters 0,1), leave 6,7 in flight
      asm volatile("s_waitcnt vmcnt(2)" ::: "memory");
      asm volatile("s_barrier" ::: "memory");
#pragma unroll
      for (int s = 0; s < 4; ++s)               // prefetch kt+1: B rows
        load_lds_16B(srcp[s] + kpre, ldsc + nxt + dstoff[s]);

      bf16x8 bfv[4][2];
#pragma unroll
      for (int j = 0; j < 4; ++j) {
        bfv[j][0] = *(const bf16x8*)(ldsc + cur + bB + j * 2048 + e0);
        bfv[j][1] = *(const bf16x8*)(ldsc + cur + bB + j * 2048 + e1);
      }

#pragma unroll
      for (int p = 0; p < 4; ++p) {
        if (p == 1) {                           // prefetch kt+1: A steps 4,5
          load_lds_16B(srcp[4] + kpre, ldsc + nxt + dstoff[4]);
          load_lds_16B(srcp[5] + kpre, ldsc + nxt + dstoff[5]);
        }
        if (p == 2) {
          // wait kt steps 6,7 (A quarters 2,3); kt+1's 6 loads stay in flight
          asm volatile("s_waitcnt vmcnt(6)" ::: "memory");
          asm volatile("s_barrier" ::: "memory");
          load_lds_16B(srcp[6] + kpre, ldsc + nxt + dstoff[6]);
          load_lds_16B(srcp[7] + kpre, ldsc + nxt + dstoff[7]);
        }
        bf16x8 af[2][2];
#pragma unroll
        for (int ii = 0; ii < 2; ++ii) {
          const int i = p * 2 + ii;
          af[ii][0] = *(const bf16x8*)(ldsc + cur + aA + i * 2048 + e0);
          af[ii][1] = *(const bf16x8*)(ldsc + cur + aA + i * 2048 + e1);
        }
        __builtin_amdgcn_s_setprio(1);
#pragma unroll
        for (int ii = 0; ii < 2; ++ii) {
          const int i = p * 2 + ii;
#pragma unroll
          for (int j = 0; j < 4; ++j) {
            acc[i][j] = __builtin_amdgcn_mfma_f32_16x16x32_bf16(
                af[ii][0], bfv[j][0], acc[i][j], 0, 0, 0);
            acc[i][j] = __builtin_amdgcn_mfma_f32_16x16x32_bf16(
                af[ii][1], bfv[j][1], acc[i][j], 0, 0, 0);
          }
        }
        __builtin_amdgcn_s_setprio(0);
      }
    }
  }

  // epilogue: row' = am0+wr*128+i*16+(lane>>4)*4+r ; col = bn0+wc*64+j*16+cl
  // OMAP==1 scatters row' (t-major) to natural f*SEQ+t on the store side.
  const int cl = lane & 15;
  const int rq = g * 4;
#pragma unroll
  for (int j = 0; j < 4; ++j) {
    const int nc   = bn0 + wc * 64 + j * 16 + cl;
    const float bb = bias[nc];
#pragma unroll
    for (int i = 0; i < 8; ++i) {
#pragma unroll
      for (int r = 0; r < 4; ++r) {
        const int rowp = am0 + wr * 128 + i * 16 + rq + r;
        const size_t mr = (OMAP == 1)
            ? ((size_t)(rowp & 15) * SEQ + (rowp >> 4))
            : (size_t)rowp;
        C[mr * DIM_ + nc] = (OutT)(acc[i][j][r] + bb);
      }
    }
  }
}

__global__ __launch_bounds__(512, 2) void gemm_qkv(
    const bf16* __restrict__ A,
    const bf16* __restrict__ Bq, const bf16* __restrict__ Bk,
    const bf16* __restrict__ Bv,
    const float* __restrict__ bq, const float* __restrict__ bk,
    const float* __restrict__ bv,
    bf16* __restrict__ Cq, bf16* __restrict__ Ck, bf16* __restrict__ Cv) {
  __shared__ __align__(16) bf16 lds[65536];  // 128 KiB
  const int z = blockIdx.z;
  const bf16* B    = (z == 0) ? Bq : (z == 1) ? Bk : Bv;
  const float* bia = (z == 0) ? bq : (z == 1) ? bk : bv;
  bf16* C          = (z == 0) ? Cq : (z == 1) ? Ck : Cv;
  int bx, by;
  swz368(blockIdx.y * 92 + blockIdx.x, bx, by);
  gemm256_body<bf16, 0>(A, B, bia, C, lds, bx, by);
}

__global__ __launch_bounds__(512, 2) void gemm_out(
    const bf16* __restrict__ A, const bf16* __restrict__ B,
    const float* __restrict__ bias, float* __restrict__ C) {
  __shared__ __align__(16) bf16 lds[65536];
  int bx, by;
  swz368(blockIdx.y * 92 + blockIdx.x, bx, by);
  gemm256_body<float, 1>(A, B, bias, C, lds, bx, by);
}

// ---------------------------------------------------------------------------
// In-place RMSNorm + RoPE on t-major rows. Wave per row, 4 rows per block.
// ---------------------------------------------------------------------------
__global__ __launch_bounds__(256) void norm_rope(
    bf16* __restrict__ q, bf16* __restrict__ k,
    const float* __restrict__ nqw, const float* __restrict__ nkw,
    const float* __restrict__ fcos, const float* __restrict__ fsin) {
  const int lane = threadIdx.x & 63, wave = threadIdx.x >> 6;
  const size_t row  = (size_t)blockIdx.x * 4 + wave;   // t-major row'
  const size_t base = row * DIM_;
  const size_t pos  = (row & 15) * (size_t)SEQ + (row >> 4);  // f*SEQ + t
  const int e0 = lane * 16;
  const int j0 = (lane & 3) * 8;

  float cs[8], sn[8];
#pragma unroll
  for (int i = 0; i < 8; ++i) {
    cs[i] = fcos[pos * 32 + j0 + i];
    sn[i] = fsin[pos * 32 + j0 + i];
  }

  bf16x8 qa = *(const bf16x8*)(q + base + e0);
  bf16x8 qb = *(const bf16x8*)(q + base + e0 + 8);
  bf16x8 ka = *(const bf16x8*)(k + base + e0);
  bf16x8 kb = *(const bf16x8*)(k + base + e0 + 8);

  float xq[16], xk[16];
#pragma unroll
  for (int i = 0; i < 8; ++i) {
    xq[i] = (float)qa[i]; xq[8 + i] = (float)qb[i];
    xk[i] = (float)ka[i]; xk[8 + i] = (float)kb[i];
  }
  float sq = 0.f, sk = 0.f;
#pragma unroll
  for (int i = 0; i < 16; ++i) { sq += xq[i] * xq[i]; sk += xk[i] * xk[i]; }
#pragma unroll
  for (int off = 32; off > 0; off >>= 1) {
    sq += __shfl_xor(sq, off);
    sk += __shfl_xor(sk, off);
  }
  const float rq = rsqrtf(sq * (1.0f / 1024.0f) + 1e-6f);
  const float rk = rsqrtf(sk * (1.0f / 1024.0f) + 1e-6f);
#pragma unroll
  for (int i = 0; i < 16; ++i) {
    xq[i] *= rq * nqw[e0 + i];
    xk[i] *= rk * nkw[e0 + i];
  }
  bf16x8 oa, ob, oc, od;
#pragma unroll
  for (int p = 0; p < 8; ++p) {
    const float c = cs[p], s = sn[p];
    const float q0 = xq[2 * p], q1 = xq[2 * p + 1];
    const float k0 = xk[2 * p], k1 = xk[2 * p + 1];
    const float qr = q0 * c - q1 * s, qi = q0 * s + q1 * c;
    const float kr = k0 * c - k1 * s, ki = k0 * s + k1 * c;
    if (p < 4) { oa[2 * p] = (bf16)qr; oa[2 * p + 1] = (bf16)qi;
                 oc[2 * p] = (bf16)kr; oc[2 * p + 1] = (bf16)ki; }
    else       { ob[2 * p - 8] = (bf16)qr; ob[2 * p - 7] = (bf16)qi;
                 od[2 * p - 8] = (bf16)kr; od[2 * p - 7] = (bf16)ki; }
  }
  *(bf16x8*)(q + base + e0)     = oa;
  *(bf16x8*)(q + base + e0 + 8) = ob;
  *(bf16x8*)(k + base + e0)     = oc;
  *(bf16x8*)(k + base + e0 + 8) = od;
}

// ---------------------------------------------------------------------------
// Windowed attention, t-major layout: block per t, all data in one 32KB slab.
// ---------------------------------------------------------------------------
__global__ __launch_bounds__(512, 4) void attn_win(
    const bf16* __restrict__ q, const bf16* __restrict__ k,
    const bf16* __restrict__ v, bf16* __restrict__ o) {
  __shared__ __align__(16) bf16 ks[16 * KROW];
  __shared__ __align__(16) bf16 vs[16 * KROW];
  __shared__ __align__(16) bf16 ps[16 * 256];  // [h][fq][fk]
  const int t    = blockIdx.x;
  const int tid  = threadIdx.x;
  const int wave = tid >> 6, lane = tid & 63;
  const size_t tb = (size_t)t * (16 * DIM_);   // base elem of t's slab

  // phase 1: stream k,v (2 x 32KB contiguous) into LDS
#pragma unroll
  for (int i = 0; i < 4; ++i) {
    const int j = wave * 4 + i;  // 0..31
    const int r = j >> 1, half = j & 1;
    const size_t g = tb + (size_t)r * DIM_ + half * 512 + lane * 8;
    load_lds_16B(k + g, ks + r * KROW + half * 512);
    load_lds_16B(v + g, vs + r * KROW + half * 512);
  }
  __syncthreads();

  // phase 2: scores via MFMA + softmax; wave handles heads wave*2, wave*2+1
  const int fl  = lane & 15;
  const int kq  = (lane >> 4) * 8;
#pragma unroll
  for (int hh = 0; hh < 2; ++hh) {
    const int h = wave * 2 + hh;
    const size_t qg = tb + (size_t)fl * DIM_ + h * HD_ + kq;
    bf16x8 aq0 = *(const bf16x8*)(q + qg);
    bf16x8 aq1 = *(const bf16x8*)(q + qg + 32);
    const int ko = fl * KROW + h * HD_ + kq;
    bf16x8 bk0 = *(const bf16x8*)(ks + ko);
    bf16x8 bk1 = *(const bf16x8*)(ks + ko + 32);
    f32x4 sc = {0.f, 0.f, 0.f, 0.f};
    sc = __builtin_amdgcn_mfma_f32_16x16x32_bf16(aq0, bk0, sc, 0, 0, 0);
    sc = __builtin_amdgcn_mfma_f32_16x16x32_bf16(aq1, bk1, sc, 0, 0, 0);
#pragma unroll
    for (int r = 0; r < 4; ++r) {
      const int row = (lane >> 4) * 4 + r;  // fq
      const bool valid = (fl <= row) && (row - fl < 8);
      float s = valid ? sc[r] * 0.125f : -1e30f;
      float m = s;
#pragma unroll
      for (int off = 8; off > 0; off >>= 1) m = fmaxf(m, __shfl_xor(m, off));
      const float e = __expf(s - m);
      float su = e;
#pragma unroll
      for (int off = 8; off > 0; off >>= 1) su += __shfl_xor(su, off);
      ps[h * 256 + row * 16 + fl] = (bf16)(e / su);
    }
  }
  __syncthreads();

  // phase 3: PV, register-blocked. thread = (h, d-chunk, fq-group)
  const int h3 = tid >> 5;
  const int dc = (tid >> 2) & 7;
  const int fg = tid & 3;
  bf16x8 pr[8];
#pragma unroll
  for (int i = 0; i < 4; ++i) {
    pr[2 * i]     = *(const bf16x8*)(ps + h3 * 256 + (fg * 4 + i) * 16);
    pr[2 * i + 1] = *(const bf16x8*)(ps + h3 * 256 + (fg * 4 + i) * 16 + 8);
  }
  float acc[4][8];
#pragma unroll
  for (int i = 0; i < 4; ++i)
#pragma unroll
    for (int d = 0; d < 8; ++d) acc[i][d] = 0.f;

  const bf16* vb = vs + h3 * HD_ + dc * 8;
#pragma unroll
  for (int fk2 = 0; fk2 < 16; ++fk2) {
    bf16x8 vv8 = *(const bf16x8*)(vb + fk2 * KROW);
    float vf[8];
#pragma unroll
    for (int d = 0; d < 8; ++d) vf[d] = (float)vv8[d];
#pragma unroll
    for (int i = 0; i < 4; ++i) {
      const float pp = (float)((fk2 < 8) ? pr[2 * i][fk2] : pr[2 * i + 1][fk2 - 8]);
#pragma unroll
      for (int d = 0; d < 8; ++d) acc[i][d] += pp * vf[d];
    }
  }
#pragma unroll
  for (int i = 0; i < 4; ++i) {
    bf16x8 ov;
#pragma unroll
    for (int d = 0; d < 8; ++d) ov[d] = (bf16)acc[i][d];
    *(bf16x8*)(o + tb + (size_t)(fg * 4 + i) * DIM_ + h3 * HD_ + dc * 8) = ov;
  }
}

// ---------------------------------------------------------------------------
extern "C" void kernel_launch(void* const* d_in, const int* in_sizes, int n_in,
                              void* d_out, int out_size, void* d_ws,
                              size_t ws_size, hipStream_t stream) {
  const float* x    = (const float*)d_in[0];
  const float* fcos = (const float*)d_in[1];
  const float* fsin = (const float*)d_in[2];
  const float* q_w  = (const float*)d_in[3];
  const float* q_b  = (const float*)d_in[4];
  const float* k_w  = (const float*)d_in[5];
  const float* k_b  = (const float*)d_in[6];
  const float* v_w  = (const float*)d_in[7];
  const float* v_b  = (const float*)d_in[8];
  const float* o_w  = (const float*)d_in[9];
  const float* o_b  = (const float*)d_in[10];
  const float* nqw  = (const float*)d_in[11];
  const float* nkw  = (const float*)d_in[12];
  float* out = (float*)d_out;

  char* ws = (char*)d_ws;
  const size_t SZ  = (size_t)TOK * DIM_ * 2;
  const size_t WSZ = (size_t)DIM_ * DIM_ * 2;
  bf16* xb = (bf16*)(ws);
  bf16* wq = (bf16*)(ws + SZ);
  bf16* wk = (bf16*)(ws + SZ + WSZ);
  bf16* wv = (bf16*)(ws + SZ + 2 * WSZ);
  bf16* wo = (bf16*)(ws + SZ + 3 * WSZ);
  bf16* qq = (bf16*)(ws + SZ + 4 * WSZ);
  bf16* kk = (bf16*)(ws + SZ + 4 * WSZ + SZ);
  bf16* vv = (bf16*)(ws + SZ + 4 * WSZ + 2 * SZ);
  bf16* om = xb;  // x_bf16 dead after gemm_qkv; reuse for attention output

  const int NTOT = TOK * DIM_;
  const int NW   = DIM_ * DIM_;

  cvt_bf16<<<NTOT / 2048, 256, 0, stream>>>(x, xb, NTOT);
  cvt_w4<<<dim3(NW / 2048, 4), 256, 0, stream>>>(q_w, k_w, v_w, o_w,
                                                 wq, wk, wv, wo);

  dim3 gq(TOK / 256, DIM_ / 256, 3);  // (92, 4, 3)
  gemm_qkv<<<gq, 512, 0, stream>>>(xb, wq, wk, wv, q_b, k_b, v_b, qq, kk, vv);

  norm_rope<<<TOK / 4, 256, 0, stream>>>(qq, kk, nqw, nkw, fcos, fsin);

  attn_win<<<SEQ, 512, 0, stream>>>(qq, kk, vv, om);

  gemm_out<<<dim3(TOK / 256, DIM_ / 256), 512, 0, stream>>>(om, wo, o_b, out);
}

// Round 4
// 505.348 us; speedup vs baseline: 1.1212x; 1.0617x over previous
//
#include <hip/hip_runtime.h>
#include <hip/hip_bf16.h>
#include <math.h>

typedef __bf16 bf16;
typedef bf16 bf16x8 __attribute__((ext_vector_type(8)));
typedef bf16 bf16x4 __attribute__((ext_vector_type(4)));
typedef float f32x4 __attribute__((ext_vector_type(4)));

#define NFRM 16
#define SEQ  1472
#define TOK  (NFRM * SEQ)   /* 23552 */
#define DIM_ 1024
#define NH_  16
#define HD_  64
#define KROW 1032           /* LDS row stride (bf16) for attn k/v: 1024 + 8 pad */

// Internal layout is T-MAJOR everywhere: row' = t*16 + f. x is permuted to
// t-major at the cvt step, so BOTH GEMMs stage A with contiguous panels.
// gemm_out permutes rows on the C-write side (stores are latency-tolerant).
// RMSNorm+RoPE is fused into attn_win (each q/k row belongs to exactly one
// attention block), eliminating the standalone norm_rope pass.

__device__ __forceinline__ void load_lds_16B(const void* g, void* l) {
  __builtin_amdgcn_global_load_lds(
      (const __attribute__((address_space(1))) unsigned int*)g,
      (__attribute__((address_space(3))) unsigned int*)l,
      16, 0, 0);
}

// ---------------------------------------------------------------------------
// f32 -> bf16 with f-major -> t-major row permutation. Reads are linear;
// writes are 2KB-contiguous per input row (threads of a row write one row').
__global__ __launch_bounds__(256) void cvt_bf16(const float* __restrict__ s,
                                                bf16* __restrict__ d, int n) {
  size_t i = ((size_t)blockIdx.x * 256 + threadIdx.x) * 8;
  if (i >= (size_t)n) return;
  const int r   = (int)(i >> 10);       // natural row = f*SEQ + t
  const int col = (int)(i & 1023);
  const int f   = r / SEQ;
  const int t   = r - f * SEQ;
  const size_t o = ((size_t)(t * 16 + f) << 10) + col;
  f32x4 a = *(const f32x4*)(s + i);
  f32x4 b = *(const f32x4*)(s + i + 4);
  bf16x8 v;
  v[0] = (bf16)a[0]; v[1] = (bf16)a[1]; v[2] = (bf16)a[2]; v[3] = (bf16)a[3];
  v[4] = (bf16)b[0]; v[5] = (bf16)b[1]; v[6] = (bf16)b[2]; v[7] = (bf16)b[3];
  *(bf16x8*)(d + o) = v;
}

__global__ __launch_bounds__(256) void cvt_w4(
    const float* __restrict__ w0, const float* __restrict__ w1,
    const float* __restrict__ w2, const float* __restrict__ w3,
    bf16* __restrict__ d0, bf16* __restrict__ d1,
    bf16* __restrict__ d2, bf16* __restrict__ d3) {
  const int z = blockIdx.y;
  const float* s = (z == 0) ? w0 : (z == 1) ? w1 : (z == 2) ? w2 : w3;
  bf16* d       = (z == 0) ? d0 : (z == 1) ? d1 : (z == 2) ? d2 : d3;
  size_t i = ((size_t)blockIdx.x * 256 + threadIdx.x) * 8;
  f32x4 a = *(const f32x4*)(s + i);
  f32x4 b = *(const f32x4*)(s + i + 4);
  bf16x8 o;
  o[0] = (bf16)a[0]; o[1] = (bf16)a[1]; o[2] = (bf16)a[2]; o[3] = (bf16)a[3];
  o[4] = (bf16)b[0]; o[5] = (bf16)b[1]; o[6] = (bf16)b[2]; o[7] = (bf16)b[3];
  *(bf16x8*)(d + i) = o;
}

// ---------------------------------------------------------------------------
// XCD-grouping swizzle for a 92x4 plane (368 = 8*46 blocks). s=(h&7)*46+(h>>3)
// gives XCD c the consecutive work range [46c,46c+46) -> the 4 y-sharers of an
// A-panel run adjacently on ONE XCD; B set/XCD = 2MB (fits L2).
__device__ __forceinline__ void swz368(int h, int& bx, int& by) {
  const int s = (h & 7) * 46 + (h >> 3);
  bx = s >> 2;
  by = s & 3;
}

// ---------------------------------------------------------------------------
// 256x256-tile, BK=64, 8-wave (2M x 4N) double-buffered GEMM, coarse 2-wait
// schedule (best measured). A rows contiguous (t-major input). OMAP: 0 = C
// rows t-major (identity), 1 = C row' t*16+f scattered to natural f*SEQ+t.
// Swizzle: byte ^= (row&7)<<4 on 16B chunks, applied on the staging *source*
// address (lane-constant XOR) and folded into read offsets.
// ---------------------------------------------------------------------------
template <typename OutT, int OMAP>
__device__ __forceinline__ void gemm256_body(const bf16* __restrict__ A,
                                             const bf16* __restrict__ B,
                                             const float* __restrict__ bias,
                                             OutT* __restrict__ C,
                                             bf16* lds, int bx, int by) {
  const int tid  = threadIdx.x;
  const int w    = tid >> 6;
  const int lane = tid & 63;
  const int am0  = bx * 256;
  const int bn0  = by * 256;

  // ---- staging setup: 8 steps/K-tile, 64 rows x 128B each ----
  const int rstep = w * 8 + (lane >> 3);                  // row within a step
  const int jsrc  = ((lane & 7) ^ ((lane >> 3) & 7)) * 8; // swizzled src chunk
  const int arb[4] = {0, 128, 64, 192};                   // A step row bases
  const bf16* srcp[8];
  int dstoff[8];
#pragma unroll
  for (int s = 0; s < 4; ++s) {
    // steps 0-3: B rows (needed by every wave's phase 0 -> staged first)
    srcp[s]   = B + (size_t)(bn0 + s * 64 + rstep) * DIM_ + jsrc;
    dstoff[s] = 32768 + s * 8192 + w * 1024;
    // steps 4-7: A rows {0-63,128-191,64-127,192-255} (quarter-interleaved);
    // contiguous panel streaming (identity row map).
    srcp[4 + s]   = A + (size_t)(am0 + arb[s] + rstep) * DIM_ + jsrc;
    dstoff[4 + s] = arb[s] * 128 + w * 1024;
  }

  // ---- fragment read offsets (bytes, swizzle folded in) ----
  const int wr   = w >> 2;       // 0..1  (M half)
  const int wc   = w & 3;        // 0..3  (N quarter)
  const int frow = lane & 15;
  const int g    = lane >> 4;
  const int sw   = (frow & 7) << 4;
  const int e0   = (g * 16) ^ sw;        // k-step 0
  const int e1   = (g * 16 + 64) ^ sw;   // k-step 1
  const int aA   = (wr * 128 + frow) * 128;
  const int bB   = 32768 + (wc * 64 + frow) * 128;

  f32x4 acc[8][4];
#pragma unroll
  for (int i = 0; i < 8; ++i)
#pragma unroll
    for (int j = 0; j < 4; ++j) {
      f32x4 z = {0.f, 0.f, 0.f, 0.f};
      acc[i][j] = z;
    }

  char* ldsc = (char*)lds;

  // prologue: stage K-tile 0 into buf0 (issue order 0..7 fixed for vmcnt math)
#pragma unroll
  for (int s = 0; s < 8; ++s) load_lds_16B(srcp[s], ldsc + dstoff[s]);

#pragma unroll 1
  for (int it = 0; it < 8; ++it) {
#pragma unroll
    for (int half = 0; half < 2; ++half) {
      const int kt   = it * 2 + half;
      const int cur  = half ? 65536 : 0;
      const int nxt  = half ? 0 : 65536;
      const int kpre = (kt < 15) ? (kt + 1) * 64 : 15 * 64;  // dummy at kt=15

      // phase 0: wait kt steps 0-5 (B + A quarters 0,1), leave 6,7 in flight
      asm volatile("s_waitcnt vmcnt(2)" ::: "memory");
      asm volatile("s_barrier" ::: "memory");
#pragma unroll
      for (int s = 0; s < 4; ++s)               // prefetch kt+1: B rows
        load_lds_16B(srcp[s] + kpre, ldsc + nxt + dstoff[s]);

      bf16x8 bfv[4][2];
#pragma unroll
      for (int j = 0; j < 4; ++j) {
        bfv[j][0] = *(const bf16x8*)(ldsc + cur + bB + j * 2048 + e0);
        bfv[j][1] = *(const bf16x8*)(ldsc + cur + bB + j * 2048 + e1);
      }

#pragma unroll
      for (int p = 0; p < 4; ++p) {
        if (p == 1) {                           // prefetch kt+1: A steps 4,5
          load_lds_16B(srcp[4] + kpre, ldsc + nxt + dstoff[4]);
          load_lds_16B(srcp[5] + kpre, ldsc + nxt + dstoff[5]);
        }
        if (p == 2) {
          // wait kt steps 6,7 (A quarters 2,3); kt+1's 6 loads stay in flight
          asm volatile("s_waitcnt vmcnt(6)" ::: "memory");
          asm volatile("s_barrier" ::: "memory");
          load_lds_16B(srcp[6] + kpre, ldsc + nxt + dstoff[6]);
          load_lds_16B(srcp[7] + kpre, ldsc + nxt + dstoff[7]);
        }
        bf16x8 af[2][2];
#pragma unroll
        for (int ii = 0; ii < 2; ++ii) {
          const int i = p * 2 + ii;
          af[ii][0] = *(const bf16x8*)(ldsc + cur + aA + i * 2048 + e0);
          af[ii][1] = *(const bf16x8*)(ldsc + cur + aA + i * 2048 + e1);
        }
        __builtin_amdgcn_s_setprio(1);
#pragma unroll
        for (int ii = 0; ii < 2; ++ii) {
          const int i = p * 2 + ii;
#pragma unroll
          for (int j = 0; j < 4; ++j) {
            acc[i][j] = __builtin_amdgcn_mfma_f32_16x16x32_bf16(
                af[ii][0], bfv[j][0], acc[i][j], 0, 0, 0);
            acc[i][j] = __builtin_amdgcn_mfma_f32_16x16x32_bf16(
                af[ii][1], bfv[j][1], acc[i][j], 0, 0, 0);
          }
        }
        __builtin_amdgcn_s_setprio(0);
      }
    }
  }

  // epilogue: row' = am0+wr*128+i*16+(lane>>4)*4+r ; col = bn0+wc*64+j*16+cl
  // OMAP==1 scatters row' (t-major) to natural f*SEQ+t on the store side.
  const int cl = lane & 15;
  const int rq = g * 4;
#pragma unroll
  for (int j = 0; j < 4; ++j) {
    const int nc   = bn0 + wc * 64 + j * 16 + cl;
    const float bb = bias[nc];
#pragma unroll
    for (int i = 0; i < 8; ++i) {
#pragma unroll
      for (int r = 0; r < 4; ++r) {
        const int rowp = am0 + wr * 128 + i * 16 + rq + r;
        const size_t mr = (OMAP == 1)
            ? ((size_t)(rowp & 15) * SEQ + (rowp >> 4))
            : (size_t)rowp;
        C[mr * DIM_ + nc] = (OutT)(acc[i][j][r] + bb);
      }
    }
  }
}

__global__ __launch_bounds__(512, 2) void gemm_qkv(
    const bf16* __restrict__ A,
    const bf16* __restrict__ Bq, const bf16* __restrict__ Bk,
    const bf16* __restrict__ Bv,
    const float* __restrict__ bq, const float* __restrict__ bk,
    const float* __restrict__ bv,
    bf16* __restrict__ Cq, bf16* __restrict__ Ck, bf16* __restrict__ Cv) {
  __shared__ __align__(16) bf16 lds[65536];  // 128 KiB
  const int z = blockIdx.z;
  const bf16* B    = (z == 0) ? Bq : (z == 1) ? Bk : Bv;
  const float* bia = (z == 0) ? bq : (z == 1) ? bk : bv;
  bf16* C          = (z == 0) ? Cq : (z == 1) ? Ck : Cv;
  int bx, by;
  swz368(blockIdx.y * 92 + blockIdx.x, bx, by);
  gemm256_body<bf16, 0>(A, B, bia, C, lds, bx, by);
}

__global__ __launch_bounds__(512, 2) void gemm_out(
    const bf16* __restrict__ A, const bf16* __restrict__ B,
    const float* __restrict__ bias, float* __restrict__ C) {
  __shared__ __align__(16) bf16 lds[65536];
  int bx, by;
  swz368(blockIdx.y * 92 + blockIdx.x, bx, by);
  gemm256_body<float, 1>(A, B, bias, C, lds, bx, by);
}

// ---------------------------------------------------------------------------
// Windowed attention with fused RMSNorm+RoPE, t-major layout: block per t.
// LDS: ks (k slab), xs (q slab, reclaimed for v after phase 2), ps. 74 KB ->
// 2 blocks/CU. v is prefetched to registers at entry (issue-early/write-late;
// the phase-2 __syncthreads drains vmcnt before the LDS write).
// ---------------------------------------------------------------------------
__global__ __launch_bounds__(512, 4) void attn_win(
    const bf16* __restrict__ q, const bf16* __restrict__ k,
    const bf16* __restrict__ v, bf16* __restrict__ o,
    const float* __restrict__ nqw, const float* __restrict__ nkw,
    const float* __restrict__ fcos, const float* __restrict__ fsin) {
  __shared__ __align__(16) bf16 ks[16 * KROW];
  __shared__ __align__(16) bf16 xs[16 * KROW];  // q slab, then v slab
  __shared__ __align__(16) bf16 ps[16 * 256];   // [h][fq][fk]
  const int t    = blockIdx.x;
  const int tid  = threadIdx.x;
  const int wave = tid >> 6, lane = tid & 63;
  const size_t tb = (size_t)t * (16 * DIM_);   // base elem of t's slab

  // v -> registers, issued first so HBM latency hides under norm + phase 2
  const bf16* vg = v + tb + (size_t)tid * 32;
  bf16x8 vr0 = *(const bf16x8*)(vg);
  bf16x8 vr1 = *(const bf16x8*)(vg + 8);
  bf16x8 vr2 = *(const bf16x8*)(vg + 16);
  bf16x8 vr3 = *(const bf16x8*)(vg + 24);

  // phase 1: stage k,q (2 x 32KB contiguous) into LDS
#pragma unroll
  for (int i = 0; i < 4; ++i) {
    const int j = wave * 4 + i;  // 0..31
    const int r = j >> 1, half = j & 1;
    const size_t g = tb + (size_t)r * DIM_ + half * 512 + lane * 8;
    load_lds_16B(k + g, ks + r * KROW + half * 512);
    load_lds_16B(q + g, xs + r * KROW + half * 512);
  }
  __syncthreads();

  // phase 1.5: RMSNorm + RoPE in LDS. wave handles 4 of 32 rows (16 q + 16 k).
#pragma unroll
  for (int i = 0; i < 4; ++i) {
    const int m  = wave * 4 + i;
    const int fr = m & 15;
    bf16* rowp = ((m < 16) ? xs : ks) + fr * KROW;
    const float* nw = (m < 16) ? nqw : nkw;
    bf16x8 a = *(const bf16x8*)(rowp + lane * 8);
    bf16x8 b = *(const bf16x8*)(rowp + 512 + lane * 8);
    float xa[8], xb[8];
    float ssq = 0.f;
#pragma unroll
    for (int e = 0; e < 8; ++e) {
      xa[e] = (float)a[e]; xb[e] = (float)b[e];
      ssq += xa[e] * xa[e] + xb[e] * xb[e];
    }
#pragma unroll
    for (int off = 32; off > 0; off >>= 1) ssq += __shfl_xor(ssq, off);
    const float rs = rsqrtf(ssq * (1.0f / 1024.0f) + 1e-6f);
    float wA[8], wB[8];
    f32x4 w0 = *(const f32x4*)(nw + lane * 8);
    f32x4 w1 = *(const f32x4*)(nw + lane * 8 + 4);
    f32x4 w2 = *(const f32x4*)(nw + 512 + lane * 8);
    f32x4 w3 = *(const f32x4*)(nw + 512 + lane * 8 + 4);
#pragma unroll
    for (int e = 0; e < 4; ++e) {
      wA[e] = w0[e]; wA[4 + e] = w1[e];
      wB[e] = w2[e]; wB[4 + e] = w3[e];
    }
    // cols lane*8.. and 512+lane*8.. share freq idx j = (lane&7)*4 + p
    const size_t pos = (size_t)fr * SEQ + t;
    f32x4 cc = *(const f32x4*)(fcos + pos * 32 + (lane & 7) * 4);
    f32x4 sn = *(const f32x4*)(fsin + pos * 32 + (lane & 7) * 4);
    bf16x8 oa, ob;
#pragma unroll
    for (int p = 0; p < 4; ++p) {
      const float a0 = xa[2 * p] * rs * wA[2 * p];
      const float a1 = xa[2 * p + 1] * rs * wA[2 * p + 1];
      const float b0 = xb[2 * p] * rs * wB[2 * p];
      const float b1 = xb[2 * p + 1] * rs * wB[2 * p + 1];
      oa[2 * p]     = (bf16)(a0 * cc[p] - a1 * sn[p]);
      oa[2 * p + 1] = (bf16)(a0 * sn[p] + a1 * cc[p]);
      ob[2 * p]     = (bf16)(b0 * cc[p] - b1 * sn[p]);
      ob[2 * p + 1] = (bf16)(b0 * sn[p] + b1 * cc[p]);
    }
    *(bf16x8*)(rowp + lane * 8)       = oa;
    *(bf16x8*)(rowp + 512 + lane * 8) = ob;
  }
  __syncthreads();

  // phase 2: scores via MFMA + softmax; wave handles heads wave*2, wave*2+1
  const int fl  = lane & 15;
  const int kq  = (lane >> 4) * 8;
#pragma unroll
  for (int hh = 0; hh < 2; ++hh) {
    const int h = wave * 2 + hh;
    const int qo = fl * KROW + h * HD_ + kq;
    bf16x8 aq0 = *(const bf16x8*)(xs + qo);
    bf16x8 aq1 = *(const bf16x8*)(xs + qo + 32);
    bf16x8 bk0 = *(const bf16x8*)(ks + qo);
    bf16x8 bk1 = *(const bf16x8*)(ks + qo + 32);
    f32x4 sc = {0.f, 0.f, 0.f, 0.f};
    sc = __builtin_amdgcn_mfma_f32_16x16x32_bf16(aq0, bk0, sc, 0, 0, 0);
    sc = __builtin_amdgcn_mfma_f32_16x16x32_bf16(aq1, bk1, sc, 0, 0, 0);
#pragma unroll
    for (int r = 0; r < 4; ++r) {
      const int row = (lane >> 4) * 4 + r;  // fq
      const bool valid = (fl <= row) && (row - fl < 8);
      float s = valid ? sc[r] * 0.125f : -1e30f;
      float m = s;
#pragma unroll
      for (int off = 8; off > 0; off >>= 1) m = fmaxf(m, __shfl_xor(m, off));
      const float e = __expf(s - m);
      float su = e;
#pragma unroll
      for (int off = 8; off > 0; off >>= 1) su += __shfl_xor(su, off);
      ps[h * 256 + row * 16 + fl] = (bf16)(e / su);
    }
  }
  __syncthreads();  // also drains the vr global loads (vmcnt(0) at barrier)

  // q slab dead; write v into xs. thread -> 64B of one row.
  {
    bf16* vd = xs + (tid >> 5) * KROW + (tid & 31) * 32;
    *(bf16x8*)(vd)      = vr0;
    *(bf16x8*)(vd + 8)  = vr1;
    *(bf16x8*)(vd + 16) = vr2;
    *(bf16x8*)(vd + 24) = vr3;
  }
  __syncthreads();

  // phase 3: PV, register-blocked. thread = (h, d-chunk, fq-group)
  const int h3 = tid >> 5;
  const int dc = (tid >> 2) & 7;
  const int fg = tid & 3;
  bf16x8 pr[8];
#pragma unroll
  for (int i = 0; i < 4; ++i) {
    pr[2 * i]     = *(const bf16x8*)(ps + h3 * 256 + (fg * 4 + i) * 16);
    pr[2 * i + 1] = *(const bf16x8*)(ps + h3 * 256 + (fg * 4 + i) * 16 + 8);
  }
  float acc[4][8];
#pragma unroll
  for (int i = 0; i < 4; ++i)
#pragma unroll
    for (int d = 0; d < 8; ++d) acc[i][d] = 0.f;

  const bf16* vb = xs + h3 * HD_ + dc * 8;
#pragma unroll
  for (int fk2 = 0; fk2 < 16; ++fk2) {
    bf16x8 vv8 = *(const bf16x8*)(vb + fk2 * KROW);
    float vf[8];
#pragma unroll
    for (int d = 0; d < 8; ++d) vf[d] = (float)vv8[d];
#pragma unroll
    for (int i = 0; i < 4; ++i) {
      const float pp = (float)((fk2 < 8) ? pr[2 * i][fk2] : pr[2 * i + 1][fk2 - 8]);
#pragma unroll
      for (int d = 0; d < 8; ++d) acc[i][d] += pp * vf[d];
    }
  }
#pragma unroll
  for (int i = 0; i < 4; ++i) {
    bf16x8 ov;
#pragma unroll
    for (int d = 0; d < 8; ++d) ov[d] = (bf16)acc[i][d];
    *(bf16x8*)(o + tb + (size_t)(fg * 4 + i) * DIM_ + h3 * HD_ + dc * 8) = ov;
  }
}

// ---------------------------------------------------------------------------
extern "C" void kernel_launch(void* const* d_in, const int* in_sizes, int n_in,
                              void* d_out, int out_size, void* d_ws,
                              size_t ws_size, hipStream_t stream) {
  const float* x    = (const float*)d_in[0];
  const float* fcos = (const float*)d_in[1];
  const float* fsin = (const float*)d_in[2];
  const float* q_w  = (const float*)d_in[3];
  const float* q_b  = (const float*)d_in[4];
  const float* k_w  = (const float*)d_in[5];
  const float* k_b  = (const float*)d_in[6];
  const float* v_w  = (const float*)d_in[7];
  const float* v_b  = (const float*)d_in[8];
  const float* o_w  = (const float*)d_in[9];
  const float* o_b  = (const float*)d_in[10];
  const float* nqw  = (const float*)d_in[11];
  const float* nkw  = (const float*)d_in[12];
  float* out = (float*)d_out;

  char* ws = (char*)d_ws;
  const size_t SZ  = (size_t)TOK * DIM_ * 2;
  const size_t WSZ = (size_t)DIM_ * DIM_ * 2;
  bf16* xb = (bf16*)(ws);
  bf16* wq = (bf16*)(ws + SZ);
  bf16* wk = (bf16*)(ws + SZ + WSZ);
  bf16* wv = (bf16*)(ws + SZ + 2 * WSZ);
  bf16* wo = (bf16*)(ws + SZ + 3 * WSZ);
  bf16* qq = (bf16*)(ws + SZ + 4 * WSZ);
  bf16* kk = (bf16*)(ws + SZ + 4 * WSZ + SZ);
  bf16* vv = (bf16*)(ws + SZ + 4 * WSZ + 2 * SZ);
  bf16* om = xb;  // x_bf16 dead after gemm_qkv; reuse for attention output

  const int NTOT = TOK * DIM_;
  const int NW   = DIM_ * DIM_;

  cvt_bf16<<<NTOT / 2048, 256, 0, stream>>>(x, xb, NTOT);
  cvt_w4<<<dim3(NW / 2048, 4), 256, 0, stream>>>(q_w, k_w, v_w, o_w,
                                                 wq, wk, wv, wo);

  dim3 gq(TOK / 256, DIM_ / 256, 3);  // (92, 4, 3)
  gemm_qkv<<<gq, 512, 0, stream>>>(xb, wq, wk, wv, q_b, k_b, v_b, qq, kk, vv);

  attn_win<<<SEQ, 512, 0, stream>>>(qq, kk, vv, om, nqw, nkw, fcos, fsin);

  gemm_out<<<dim3(TOK / 256, DIM_ / 256), 512, 0, stream>>>(om, wo, o_b, out);
}

// Round 5
// 501.951 us; speedup vs baseline: 1.1288x; 1.0068x over previous
//
#include <hip/hip_runtime.h>
#include <hip/hip_bf16.h>
#include <math.h>

typedef __bf16 bf16;
typedef bf16 bf16x8 __attribute__((ext_vector_type(8)));
typedef bf16 bf16x4 __attribute__((ext_vector_type(4)));
typedef float f32x4 __attribute__((ext_vector_type(4)));

#define NFRM 16
#define SEQ  1472
#define TOK  (NFRM * SEQ)   /* 23552 */
#define DIM_ 1024
#define NH_  16
#define HD_  64
#define KROW 1032           /* LDS row stride (bf16) for attn k/v: 1024 + 8 pad */

// Internal layout is T-MAJOR everywhere: row' = t*16 + f. x is permuted to
// t-major at the cvt step, so BOTH GEMMs stage A with contiguous panels.
// gemm_out permutes rows on the C-write side (stores are latency-tolerant).
// RMSNorm+RoPE is fused into attn_win.

__device__ __forceinline__ void load_lds_16B(const void* g, void* l) {
  __builtin_amdgcn_global_load_lds(
      (const __attribute__((address_space(1))) unsigned int*)g,
      (__attribute__((address_space(3))) unsigned int*)l,
      16, 0, 0);
}

// ---------------------------------------------------------------------------
// f32 -> bf16 with f-major -> t-major row permutation. Reads are linear;
// writes are 2KB-contiguous per input row (threads of a row write one row').
__global__ __launch_bounds__(256) void cvt_bf16(const float* __restrict__ s,
                                                bf16* __restrict__ d, int n) {
  size_t i = ((size_t)blockIdx.x * 256 + threadIdx.x) * 8;
  if (i >= (size_t)n) return;
  const int r   = (int)(i >> 10);       // natural row = f*SEQ + t
  const int col = (int)(i & 1023);
  const int f   = r / SEQ;
  const int t   = r - f * SEQ;
  const size_t o = ((size_t)(t * 16 + f) << 10) + col;
  f32x4 a = *(const f32x4*)(s + i);
  f32x4 b = *(const f32x4*)(s + i + 4);
  bf16x8 v;
  v[0] = (bf16)a[0]; v[1] = (bf16)a[1]; v[2] = (bf16)a[2]; v[3] = (bf16)a[3];
  v[4] = (bf16)b[0]; v[5] = (bf16)b[1]; v[6] = (bf16)b[2]; v[7] = (bf16)b[3];
  *(bf16x8*)(d + o) = v;
}

__global__ __launch_bounds__(256) void cvt_w4(
    const float* __restrict__ w0, const float* __restrict__ w1,
    const float* __restrict__ w2, const float* __restrict__ w3,
    bf16* __restrict__ d0, bf16* __restrict__ d1,
    bf16* __restrict__ d2, bf16* __restrict__ d3) {
  const int z = blockIdx.y;
  const float* s = (z == 0) ? w0 : (z == 1) ? w1 : (z == 2) ? w2 : w3;
  bf16* d       = (z == 0) ? d0 : (z == 1) ? d1 : (z == 2) ? d2 : d3;
  size_t i = ((size_t)blockIdx.x * 256 + threadIdx.x) * 8;
  f32x4 a = *(const f32x4*)(s + i);
  f32x4 b = *(const f32x4*)(s + i + 4);
  bf16x8 o;
  o[0] = (bf16)a[0]; o[1] = (bf16)a[1]; o[2] = (bf16)a[2]; o[3] = (bf16)a[3];
  o[4] = (bf16)b[0]; o[5] = (bf16)b[1]; o[6] = (bf16)b[2]; o[7] = (bf16)b[3];
  *(bf16x8*)(d + i) = o;
}

// ---------------------------------------------------------------------------
// 256x256-tile, BK=64, 8-wave (2M x 4N) double-buffered GEMM, coarse 2-wait
// schedule (best measured). A rows contiguous (t-major input). C rows t-major
// (identity). Swizzle: byte ^= (row&7)<<4 on 16B chunks, applied on the
// staging *source* address (lane-constant XOR) and folded into read offsets.
// ---------------------------------------------------------------------------
__device__ __forceinline__ void gemm256_body(const bf16* __restrict__ A,
                                             const bf16* __restrict__ B,
                                             const float* __restrict__ bias,
                                             bf16* __restrict__ C,
                                             bf16* lds, int bx, int by) {
  const int tid  = threadIdx.x;
  const int w    = tid >> 6;
  const int lane = tid & 63;
  const int am0  = bx * 256;
  const int bn0  = by * 256;

  // ---- staging setup: 8 steps/K-tile, 64 rows x 128B each ----
  const int rstep = w * 8 + (lane >> 3);                  // row within a step
  const int jsrc  = ((lane & 7) ^ ((lane >> 3) & 7)) * 8; // swizzled src chunk
  const int arb[4] = {0, 128, 64, 192};                   // A step row bases
  const bf16* srcp[8];
  int dstoff[8];
#pragma unroll
  for (int s = 0; s < 4; ++s) {
    // steps 0-3: B rows (needed by every wave's phase 0 -> staged first)
    srcp[s]   = B + (size_t)(bn0 + s * 64 + rstep) * DIM_ + jsrc;
    dstoff[s] = 32768 + s * 8192 + w * 1024;
    // steps 4-7: A rows {0-63,128-191,64-127,192-255} (quarter-interleaved);
    // contiguous panel streaming (identity row map).
    srcp[4 + s]   = A + (size_t)(am0 + arb[s] + rstep) * DIM_ + jsrc;
    dstoff[4 + s] = arb[s] * 128 + w * 1024;
  }

  // ---- fragment read offsets (bytes, swizzle folded in) ----
  const int wr   = w >> 2;       // 0..1  (M half)
  const int wc   = w & 3;        // 0..3  (N quarter)
  const int frow = lane & 15;
  const int g    = lane >> 4;
  const int sw   = (frow & 7) << 4;
  const int e0   = (g * 16) ^ sw;        // k-step 0
  const int e1   = (g * 16 + 64) ^ sw;   // k-step 1
  const int aA   = (wr * 128 + frow) * 128;
  const int bB   = 32768 + (wc * 64 + frow) * 128;

  f32x4 acc[8][4];
#pragma unroll
  for (int i = 0; i < 8; ++i)
#pragma unroll
    for (int j = 0; j < 4; ++j) {
      f32x4 z = {0.f, 0.f, 0.f, 0.f};
      acc[i][j] = z;
    }

  char* ldsc = (char*)lds;

  // prologue: stage K-tile 0 into buf0 (issue order 0..7 fixed for vmcnt math)
#pragma unroll
  for (int s = 0; s < 8; ++s) load_lds_16B(srcp[s], ldsc + dstoff[s]);

#pragma unroll 1
  for (int it = 0; it < 8; ++it) {
#pragma unroll
    for (int half = 0; half < 2; ++half) {
      const int kt   = it * 2 + half;
      const int cur  = half ? 65536 : 0;
      const int nxt  = half ? 0 : 65536;
      const int kpre = (kt < 15) ? (kt + 1) * 64 : 15 * 64;  // dummy at kt=15

      // phase 0: wait kt steps 0-5 (B + A quarters 0,1), leave 6,7 in flight
      asm volatile("s_waitcnt vmcnt(2)" ::: "memory");
      asm volatile("s_barrier" ::: "memory");
#pragma unroll
      for (int s = 0; s < 4; ++s)               // prefetch kt+1: B rows
        load_lds_16B(srcp[s] + kpre, ldsc + nxt + dstoff[s]);

      bf16x8 bfv[4][2];
#pragma unroll
      for (int j = 0; j < 4; ++j) {
        bfv[j][0] = *(const bf16x8*)(ldsc + cur + bB + j * 2048 + e0);
        bfv[j][1] = *(const bf16x8*)(ldsc + cur + bB + j * 2048 + e1);
      }

#pragma unroll
      for (int p = 0; p < 4; ++p) {
        if (p == 1) {                           // prefetch kt+1: A steps 4,5
          load_lds_16B(srcp[4] + kpre, ldsc + nxt + dstoff[4]);
          load_lds_16B(srcp[5] + kpre, ldsc + nxt + dstoff[5]);
        }
        if (p == 2) {
          // wait kt steps 6,7 (A quarters 2,3); kt+1's 6 loads stay in flight
          asm volatile("s_waitcnt vmcnt(6)" ::: "memory");
          asm volatile("s_barrier" ::: "memory");
          load_lds_16B(srcp[6] + kpre, ldsc + nxt + dstoff[6]);
          load_lds_16B(srcp[7] + kpre, ldsc + nxt + dstoff[7]);
        }
        bf16x8 af[2][2];
#pragma unroll
        for (int ii = 0; ii < 2; ++ii) {
          const int i = p * 2 + ii;
          af[ii][0] = *(const bf16x8*)(ldsc + cur + aA + i * 2048 + e0);
          af[ii][1] = *(const bf16x8*)(ldsc + cur + aA + i * 2048 + e1);
        }
        __builtin_amdgcn_s_setprio(1);
#pragma unroll
        for (int ii = 0; ii < 2; ++ii) {
          const int i = p * 2 + ii;
#pragma unroll
          for (int j = 0; j < 4; ++j) {
            acc[i][j] = __builtin_amdgcn_mfma_f32_16x16x32_bf16(
                af[ii][0], bfv[j][0], acc[i][j], 0, 0, 0);
            acc[i][j] = __builtin_amdgcn_mfma_f32_16x16x32_bf16(
                af[ii][1], bfv[j][1], acc[i][j], 0, 0, 0);
          }
        }
        __builtin_amdgcn_s_setprio(0);
      }
    }
  }

  // epilogue: row = am0+wr*128+i*16+(lane>>4)*4+r ; col = bn0+wc*64+j*16+cl
  const int cl = lane & 15;
  const int rq = g * 4;
#pragma unroll
  for (int j = 0; j < 4; ++j) {
    const int nc   = bn0 + wc * 64 + j * 16 + cl;
    const float bb = bias[nc];
#pragma unroll
    for (int i = 0; i < 8; ++i) {
#pragma unroll
      for (int r = 0; r < 4; ++r) {
        const size_t mr = (size_t)(am0 + wr * 128 + i * 16 + rq + r);
        C[mr * DIM_ + nc] = (bf16)(acc[i][j][r] + bb);
      }
    }
  }
}

// z-folded bijective XCD swizzle: 1104 blocks = 8 XCDs x 138. Each XCD gets a
// contiguous s-range; within it the 12 (y,z) blocks of an A-panel (bx) run
// adjacently -> A-panel fetched from HBM once per XCD (not once per z-plane).
__global__ __launch_bounds__(512, 2) void gemm_qkv(
    const bf16* __restrict__ A,
    const bf16* __restrict__ Bq, const bf16* __restrict__ Bk,
    const bf16* __restrict__ Bv,
    const float* __restrict__ bq, const float* __restrict__ bk,
    const float* __restrict__ bv,
    bf16* __restrict__ Cq, bf16* __restrict__ Ck, bf16* __restrict__ Cv) {
  __shared__ __align__(16) bf16 lds[65536];  // 128 KiB
  const int h  = blockIdx.z * 368 + blockIdx.y * 92 + blockIdx.x;  // hw flat id
  const int s  = (h & 7) * 138 + (h >> 3);
  const int bx = s / 12;
  const int rr = s - bx * 12;
  const int z  = rr >> 2;
  const int by = rr & 3;
  const bf16* B    = (z == 0) ? Bq : (z == 1) ? Bk : Bv;
  const float* bia = (z == 0) ? bq : (z == 1) ? bk : bv;
  bf16* C          = (z == 0) ? Cq : (z == 1) ? Ck : Cv;
  gemm256_body(A, B, bia, C, lds, bx, by);
}

// ---------------------------------------------------------------------------
// gemm_out: m97/m103-class 128x128 tile, BK=32, 32 KB LDS dbuf, 256 thr /
// 4 waves (4M x 1N: wave = 32 rows x 128 cols, acc[2][8] = 64 VGPR) ->
// ~3 blocks/CU for inter-block latency overlap. Counted-vmcnt ledger:
// steps per K-tile {A0,A1,B0,B1}; ph1: vmcnt(1) (A0,A1,B0 in), prefetch
// A0',A1', B j0-3 + 8 MFMA; ph2: vmcnt(2) (B1 in), prefetch B0',B1',
// B j4-7 + 8 MFMA. Never drains to 0. Swizzle: 16B chunk ^= row&3 (64B rows),
// pre-swizzled global source + XOR'd read offsets.
// C rows scatter t-major row' -> natural f*SEQ+t (64B f32 chunks per quad).
// ---------------------------------------------------------------------------
__global__ __launch_bounds__(256, 3) void gemm_out(
    const bf16* __restrict__ A, const bf16* __restrict__ B,
    const float* __restrict__ bias, float* __restrict__ C) {
  __shared__ __align__(16) bf16 lds[16384];  // 32 KB
  const int h  = blockIdx.y * 184 + blockIdx.x;   // grid (184,8), x fastest
  const int s  = (h & 7) * 184 + (h >> 3);        // 1472 = 8*184 exact
  const int bx = s >> 3, by = s & 7;
  const int am0 = bx * 128, bn0 = by * 128;
  const int tid = threadIdx.x, w = tid >> 6, lane = tid & 63;

  // staging: 4 steps/K-tile, 64 rows x 64B each; thread -> (row, 16B chunk)
  const int rstep = tid >> 2;                        // 0..63
  const int csw   = ((tid & 3) ^ (rstep & 3)) * 8;   // swizzled src col (elems)
  const bf16* srcp[4];
  int dstoff[4];
  srcp[0] = A + (size_t)(am0 + rstep) * DIM_ + csw;       dstoff[0] = 0;
  srcp[1] = A + (size_t)(am0 + 64 + rstep) * DIM_ + csw;  dstoff[1] = 4096;
  srcp[2] = B + (size_t)(bn0 + rstep) * DIM_ + csw;       dstoff[2] = 8192;
  srcp[3] = B + (size_t)(bn0 + 64 + rstep) * DIM_ + csw;  dstoff[3] = 12288;
#pragma unroll
  for (int q = 0; q < 4; ++q) dstoff[q] += w * 1024;

  // fragment read offsets (bytes, swizzle folded in); row&3 == frow&3
  const int frow = lane & 15;
  const int g    = lane >> 4;                 // k-chunk 0..3 (8 elems each)
  const int swr  = (g ^ (frow & 3)) * 16;
  const int aoff = (w * 32 + frow) * 64 + swr;          // + i*1024
  const int boff = 8192 + frow * 64 + swr;              // + j*1024

  f32x4 acc[2][8];
#pragma unroll
  for (int i = 0; i < 2; ++i)
#pragma unroll
    for (int j = 0; j < 8; ++j) {
      f32x4 z = {0.f, 0.f, 0.f, 0.f};
      acc[i][j] = z;
    }

  char* ldsc = (char*)lds;
#pragma unroll
  for (int q = 0; q < 4; ++q) load_lds_16B(srcp[q], ldsc + dstoff[q]);

  bf16x8 af[2], bfv[4];
#pragma unroll 1
  for (int kt = 0; kt < 32; ++kt) {
    const int cur  = (kt & 1) << 14;
    const int nxt  = ((kt & 1) ^ 1) << 14;
    const int kpre = (kt < 31) ? (kt + 1) * 32 : 31 * 32;  // dummy at kt=31

    // phase 1: A0,A1,B0 landed (B1 stays in flight)
    asm volatile("s_waitcnt vmcnt(1)" ::: "memory");
    asm volatile("s_barrier" ::: "memory");
    load_lds_16B(srcp[0] + kpre, ldsc + nxt + dstoff[0]);
    load_lds_16B(srcp[1] + kpre, ldsc + nxt + dstoff[1]);
    af[0] = *(const bf16x8*)(ldsc + cur + aoff);
    af[1] = *(const bf16x8*)(ldsc + cur + aoff + 1024);
#pragma unroll
    for (int j = 0; j < 4; ++j)
      bfv[j] = *(const bf16x8*)(ldsc + cur + boff + j * 1024);
    __builtin_amdgcn_s_setprio(1);
#pragma unroll
    for (int i = 0; i < 2; ++i)
#pragma unroll
      for (int j = 0; j < 4; ++j)
        acc[i][j] = __builtin_amdgcn_mfma_f32_16x16x32_bf16(af[i], bfv[j],
                                                            acc[i][j], 0, 0, 0);
    __builtin_amdgcn_s_setprio(0);

    // phase 2: B1 landed (next tile's A0',A1' stay in flight)
    asm volatile("s_waitcnt vmcnt(2)" ::: "memory");
    asm volatile("s_barrier" ::: "memory");
    load_lds_16B(srcp[2] + kpre, ldsc + nxt + dstoff[2]);
    load_lds_16B(srcp[3] + kpre, ldsc + nxt + dstoff[3]);
#pragma unroll
    for (int j = 0; j < 4; ++j)
      bfv[j] = *(const bf16x8*)(ldsc + cur + boff + 4096 + j * 1024);
    __builtin_amdgcn_s_setprio(1);
#pragma unroll
    for (int i = 0; i < 2; ++i)
#pragma unroll
      for (int j = 0; j < 4; ++j)
        acc[i][4 + j] = __builtin_amdgcn_mfma_f32_16x16x32_bf16(
            af[i], bfv[j], acc[i][4 + j], 0, 0, 0);
    __builtin_amdgcn_s_setprio(0);
  }

  // epilogue: row' = am0 + w*32 + i*16 + g*4 + r (t-major) scattered to
  // natural f*SEQ+t; col = bn0 + j*16 + (lane&15). 16-lane 64B f32 chunks.
  const int cl = lane & 15;
  const int rq = g * 4;
#pragma unroll
  for (int j = 0; j < 8; ++j) {
    const int nc   = bn0 + j * 16 + cl;
    const float bb = bias[nc];
#pragma unroll
    for (int i = 0; i < 2; ++i) {
#pragma unroll
      for (int r = 0; r < 4; ++r) {
        const int rowp = am0 + w * 32 + i * 16 + rq + r;
        const size_t mr = (size_t)(rowp & 15) * SEQ + (rowp >> 4);
        C[mr * DIM_ + nc] = acc[i][j][r] + bb;
      }
    }
  }
}

// ---------------------------------------------------------------------------
// Windowed attention with fused RMSNorm+RoPE, t-major layout: block per t.
// LDS: ks (k slab), xs (q slab, reclaimed for v after phase 2), ps. 74 KB ->
// 2 blocks/CU. v is prefetched to registers at entry (issue-early/write-late;
// the phase-2 __syncthreads drains vmcnt before the LDS write).
// ---------------------------------------------------------------------------
__global__ __launch_bounds__(512, 4) void attn_win(
    const bf16* __restrict__ q, const bf16* __restrict__ k,
    const bf16* __restrict__ v, bf16* __restrict__ o,
    const float* __restrict__ nqw, const float* __restrict__ nkw,
    const float* __restrict__ fcos, const float* __restrict__ fsin) {
  __shared__ __align__(16) bf16 ks[16 * KROW];
  __shared__ __align__(16) bf16 xs[16 * KROW];  // q slab, then v slab
  __shared__ __align__(16) bf16 ps[16 * 256];   // [h][fq][fk]
  const int t    = blockIdx.x;
  const int tid  = threadIdx.x;
  const int wave = tid >> 6, lane = tid & 63;
  const size_t tb = (size_t)t * (16 * DIM_);   // base elem of t's slab

  // v -> registers, issued first so HBM latency hides under norm + phase 2
  const bf16* vg = v + tb + (size_t)tid * 32;
  bf16x8 vr0 = *(const bf16x8*)(vg);
  bf16x8 vr1 = *(const bf16x8*)(vg + 8);
  bf16x8 vr2 = *(const bf16x8*)(vg + 16);
  bf16x8 vr3 = *(const bf16x8*)(vg + 24);

  // phase 1: stage k,q (2 x 32KB contiguous) into LDS
#pragma unroll
  for (int i = 0; i < 4; ++i) {
    const int j = wave * 4 + i;  // 0..31
    const int r = j >> 1, half = j & 1;
    const size_t g = tb + (size_t)r * DIM_ + half * 512 + lane * 8;
    load_lds_16B(k + g, ks + r * KROW + half * 512);
    load_lds_16B(q + g, xs + r * KROW + half * 512);
  }
  __syncthreads();

  // phase 1.5: RMSNorm + RoPE in LDS. wave handles 4 of 32 rows (16 q + 16 k).
#pragma unroll
  for (int i = 0; i < 4; ++i) {
    const int m  = wave * 4 + i;
    const int fr = m & 15;
    bf16* rowp = ((m < 16) ? xs : ks) + fr * KROW;
    const float* nw = (m < 16) ? nqw : nkw;
    bf16x8 a = *(const bf16x8*)(rowp + lane * 8);
    bf16x8 b = *(const bf16x8*)(rowp + 512 + lane * 8);
    float xa[8], xb[8];
    float ssq = 0.f;
#pragma unroll
    for (int e = 0; e < 8; ++e) {
      xa[e] = (float)a[e]; xb[e] = (float)b[e];
      ssq += xa[e] * xa[e] + xb[e] * xb[e];
    }
#pragma unroll
    for (int off = 32; off > 0; off >>= 1) ssq += __shfl_xor(ssq, off);
    const float rs = rsqrtf(ssq * (1.0f / 1024.0f) + 1e-6f);
    float wA[8], wB[8];
    f32x4 w0 = *(const f32x4*)(nw + lane * 8);
    f32x4 w1 = *(const f32x4*)(nw + lane * 8 + 4);
    f32x4 w2 = *(const f32x4*)(nw + 512 + lane * 8);
    f32x4 w3 = *(const f32x4*)(nw + 512 + lane * 8 + 4);
#pragma unroll
    for (int e = 0; e < 4; ++e) {
      wA[e] = w0[e]; wA[4 + e] = w1[e];
      wB[e] = w2[e]; wB[4 + e] = w3[e];
    }
    const size_t pos = (size_t)fr * SEQ + t;
    f32x4 cc = *(const f32x4*)(fcos + pos * 32 + (lane & 7) * 4);
    f32x4 sn = *(const f32x4*)(fsin + pos * 32 + (lane & 7) * 4);
    bf16x8 oa, ob;
#pragma unroll
    for (int p = 0; p < 4; ++p) {
      const float a0 = xa[2 * p] * rs * wA[2 * p];
      const float a1 = xa[2 * p + 1] * rs * wA[2 * p + 1];
      const float b0 = xb[2 * p] * rs * wB[2 * p];
      const float b1 = xb[2 * p + 1] * rs * wB[2 * p + 1];
      oa[2 * p]     = (bf16)(a0 * cc[p] - a1 * sn[p]);
      oa[2 * p + 1] = (bf16)(a0 * sn[p] + a1 * cc[p]);
      ob[2 * p]     = (bf16)(b0 * cc[p] - b1 * sn[p]);
      ob[2 * p + 1] = (bf16)(b0 * sn[p] + b1 * cc[p]);
    }
    *(bf16x8*)(rowp + lane * 8)       = oa;
    *(bf16x8*)(rowp + 512 + lane * 8) = ob;
  }
  __syncthreads();

  // phase 2: scores via MFMA + softmax; wave handles heads wave*2, wave*2+1
  const int fl  = lane & 15;
  const int kq  = (lane >> 4) * 8;
#pragma unroll
  for (int hh = 0; hh < 2; ++hh) {
    const int h = wave * 2 + hh;
    const int qo = fl * KROW + h * HD_ + kq;
    bf16x8 aq0 = *(const bf16x8*)(xs + qo);
    bf16x8 aq1 = *(const bf16x8*)(xs + qo + 32);
    bf16x8 bk0 = *(const bf16x8*)(ks + qo);
    bf16x8 bk1 = *(const bf16x8*)(ks + qo + 32);
    f32x4 sc = {0.f, 0.f, 0.f, 0.f};
    sc = __builtin_amdgcn_mfma_f32_16x16x32_bf16(aq0, bk0, sc, 0, 0, 0);
    sc = __builtin_amdgcn_mfma_f32_16x16x32_bf16(aq1, bk1, sc, 0, 0, 0);
#pragma unroll
    for (int r = 0; r < 4; ++r) {
      const int row = (lane >> 4) * 4 + r;  // fq
      const bool valid = (fl <= row) && (row - fl < 8);
      float s = valid ? sc[r] * 0.125f : -1e30f;
      float m = s;
#pragma unroll
      for (int off = 8; off > 0; off >>= 1) m = fmaxf(m, __shfl_xor(m, off));
      const float e = __expf(s - m);
      float su = e;
#pragma unroll
      for (int off = 8; off > 0; off >>= 1) su += __shfl_xor(su, off);
      ps[h * 256 + row * 16 + fl] = (bf16)(e / su);
    }
  }
  __syncthreads();  // also drains the vr global loads

  // q slab dead; write v into xs. thread -> 64B of one row.
  {
    bf16* vd = xs + (tid >> 5) * KROW + (tid & 31) * 32;
    *(bf16x8*)(vd)      = vr0;
    *(bf16x8*)(vd + 8)  = vr1;
    *(bf16x8*)(vd + 16) = vr2;
    *(bf16x8*)(vd + 24) = vr3;
  }
  __syncthreads();

  // phase 3: PV, register-blocked. thread = (h, d-chunk, fq-group)
  const int h3 = tid >> 5;
  const int dc = (tid >> 2) & 7;
  const int fg = tid & 3;
  bf16x8 pr[8];
#pragma unroll
  for (int i = 0; i < 4; ++i) {
    pr[2 * i]     = *(const bf16x8*)(ps + h3 * 256 + (fg * 4 + i) * 16);
    pr[2 * i + 1] = *(const bf16x8*)(ps + h3 * 256 + (fg * 4 + i) * 16 + 8);
  }
  float acc[4][8];
#pragma unroll
  for (int i = 0; i < 4; ++i)
#pragma unroll
    for (int d = 0; d < 8; ++d) acc[i][d] = 0.f;

  const bf16* vb = xs + h3 * HD_ + dc * 8;
#pragma unroll
  for (int fk2 = 0; fk2 < 16; ++fk2) {
    bf16x8 vv8 = *(const bf16x8*)(vb + fk2 * KROW);
    float vf[8];
#pragma unroll
    for (int d = 0; d < 8; ++d) vf[d] = (float)vv8[d];
#pragma unroll
    for (int i = 0; i < 4; ++i) {
      const float pp = (float)((fk2 < 8) ? pr[2 * i][fk2] : pr[2 * i + 1][fk2 - 8]);
#pragma unroll
      for (int d = 0; d < 8; ++d) acc[i][d] += pp * vf[d];
    }
  }
#pragma unroll
  for (int i = 0; i < 4; ++i) {
    bf16x8 ov;
#pragma unroll
    for (int d = 0; d < 8; ++d) ov[d] = (bf16)acc[i][d];
    *(bf16x8*)(o + tb + (size_t)(fg * 4 + i) * DIM_ + h3 * HD_ + dc * 8) = ov;
  }
}

// ---------------------------------------------------------------------------
extern "C" void kernel_launch(void* const* d_in, const int* in_sizes, int n_in,
                              void* d_out, int out_size, void* d_ws,
                              size_t ws_size, hipStream_t stream) {
  const float* x    = (const float*)d_in[0];
  const float* fcos = (const float*)d_in[1];
  const float* fsin = (const float*)d_in[2];
  const float* q_w  = (const float*)d_in[3];
  const float* q_b  = (const float*)d_in[4];
  const float* k_w  = (const float*)d_in[5];
  const float* k_b  = (const float*)d_in[6];
  const float* v_w  = (const float*)d_in[7];
  const float* v_b  = (const float*)d_in[8];
  const float* o_w  = (const float*)d_in[9];
  const float* o_b  = (const float*)d_in[10];
  const float* nqw  = (const float*)d_in[11];
  const float* nkw  = (const float*)d_in[12];
  float* out = (float*)d_out;

  char* ws = (char*)d_ws;
  const size_t SZ  = (size_t)TOK * DIM_ * 2;
  const size_t WSZ = (size_t)DIM_ * DIM_ * 2;
  bf16* xb = (bf16*)(ws);
  bf16* wq = (bf16*)(ws + SZ);
  bf16* wk = (bf16*)(ws + SZ + WSZ);
  bf16* wv = (bf16*)(ws + SZ + 2 * WSZ);
  bf16* wo = (bf16*)(ws + SZ + 3 * WSZ);
  bf16* qq = (bf16*)(ws + SZ + 4 * WSZ);
  bf16* kk = (bf16*)(ws + SZ + 4 * WSZ + SZ);
  bf16* vv = (bf16*)(ws + SZ + 4 * WSZ + 2 * SZ);
  bf16* om = xb;  // x_bf16 dead after gemm_qkv; reuse for attention output

  const int NTOT = TOK * DIM_;
  const int NW   = DIM_ * DIM_;

  cvt_bf16<<<NTOT / 2048, 256, 0, stream>>>(x, xb, NTOT);
  cvt_w4<<<dim3(NW / 2048, 4), 256, 0, stream>>>(q_w, k_w, v_w, o_w,
                                                 wq, wk, wv, wo);

  dim3 gq(TOK / 256, DIM_ / 256, 3);  // (92, 4, 3)
  gemm_qkv<<<gq, 512, 0, stream>>>(xb, wq, wk, wv, q_b, k_b, v_b, qq, kk, vv);

  attn_win<<<SEQ, 512, 0, stream>>>(qq, kk, vv, om, nqw, nkw, fcos, fsin);

  gemm_out<<<dim3(TOK / 128, DIM_ / 128), 256, 0, stream>>>(om, wo, o_b, out);
}